// Round 5
// baseline (234.225 us; speedup 1.0000x reference)
//
#include <hip/hip_runtime.h>

// Problem constants
#define HB 1024   // NUM_BASIC (GEMM K)
#define HM 8192   // NUM_MIXED (GEMM M)
#define NR 735    // 105*7 actual GEMM N
#define NPAD 768  // padded N
#define NOUT 57   // output is (HM, 57, 57)

// GEMM tiling: 64x128 block tile, no LDS (operands L2/L1-resident)
#define BM 64
#define BN 128

typedef __attribute__((ext_vector_type(8))) _Float16 half8;
typedef __attribute__((ext_vector_type(4))) _Float16 half4v;
typedef __attribute__((ext_vector_type(4))) float floatx4;

// ---------------------------------------------------------------------------
// Kernel 1 (merged preps):
//  blocks [0, NPAD):        x2[r][h] = relu(te[h,t]*mat[h,n,m]) fp16,
//                           rows >= NR zeroed, K(h)-contiguous. r=(t*7+m)*7+n
//  blocks [NPAD, NPAD+8192): W fp32 -> fp16
// ---------------------------------------------------------------------------
__global__ __launch_bounds__(256) void prep_kernel(
    const float* __restrict__ mat, const float* __restrict__ tex,
    const float4* __restrict__ W,
    _Float16* __restrict__ Xh, half4v* __restrict__ Wh) {
  const int blk = blockIdx.x;
  if (blk < NPAD) {
    const int r = blk;
    const int n = r % 7;
    const int tm = r / 7;
    const int m = tm % 7;
    const int t = tm / 7;
#pragma unroll
    for (int i = 0; i < 4; ++i) {
      const int h = i * 256 + threadIdx.x;
      float v = 0.f;
      if (r < NR) {
        const float mv = mat[h * 49 + n * 7 + m];
        const float te = 1.f / (1.f + expf(-tex[h * 15 + t])) + 1.f;
        v = te * mv;
        v = v > 0.f ? v : 0.f;  // relu
      }
      Xh[r * HB + h] = (_Float16)v;
    }
  } else {
    const int idx = (blk - NPAD) * 256 + threadIdx.x;
    const float4 v = W[idx];
    half4v h;
    h.x = (_Float16)v.x;
    h.y = (_Float16)v.y;
    h.z = (_Float16)v.z;
    h.w = (_Float16)v.w;
    Wh[idx] = h;
  }
}

// ---------------------------------------------------------------------------
// Kernel 2: GEMM  Y[j][r] = relu( sum_h Wh[j][h]*Xh[r][h] + b[j] )
// M=8192, N=768, K=1024. Grid 768 = 3 blocks/CU, 4 waves each 32x64.
// NO LDS: Xh (1.5MB) and the per-XCD Wh slice (2MB) are L2-resident under
// the XCD swizzle; waves pairwise share fragment rows so L1 serves the
// intra-block reuse. No barriers -> no vmcnt-drain stalls. Fragments are
// loaded straight into MFMA layout (identical address math to the previous
// LDS-read path) with a 2-deep register ping-pong (named arrays, static
// indexing) so ~12 16B loads stay in flight under each 16-MFMA body.
// ---------------------------------------------------------------------------
#define LOADF(af, bf, k0)                                                     \
  do {                                                                        \
    _Pragma("unroll")                                                         \
    for (int s_ = 0; s_ < 2; ++s_) {                                          \
      _Pragma("unroll")                                                       \
      for (int i_ = 0; i_ < 2; ++i_)                                          \
        af[s_][i_] =                                                          \
            *(const half8*)(Abase + (size_t)i_ * 16 * HB + (k0) + s_ * 32);   \
      _Pragma("unroll")                                                       \
      for (int j_ = 0; j_ < 4; ++j_)                                          \
        bf[s_][j_] =                                                          \
            *(const half8*)(Bbase + (size_t)j_ * 16 * HB + (k0) + s_ * 32);   \
    }                                                                         \
  } while (0)

#define MFMAS(af, bf)                                                         \
  do {                                                                        \
    _Pragma("unroll")                                                         \
    for (int s_ = 0; s_ < 2; ++s_)                                            \
      _Pragma("unroll")                                                       \
      for (int i_ = 0; i_ < 2; ++i_)                                          \
        _Pragma("unroll")                                                     \
        for (int j_ = 0; j_ < 4; ++j_)                                        \
          acc[i_][j_] = __builtin_amdgcn_mfma_f32_16x16x32_f16(               \
              af[s_][i_], bf[s_][j_], acc[i_][j_], 0, 0, 0);                  \
  } while (0)

__global__ __launch_bounds__(256) void gemm_kernel(
    const _Float16* __restrict__ A,  // Wh [8192][1024]
    const _Float16* __restrict__ B,  // Xh [768][1024]
    const float* __restrict__ bias,  // [8192]
    float* __restrict__ Y) {         // [8192][768]
  const int tid = threadIdx.x;
  const int lane = tid & 63;
  const int wave = tid >> 6;

  // bijective XCD swizzle over 768 blocks (768 = 8 XCD * 96)
  const int bid = blockIdx.x;
  const int wg = (bid & 7) * 96 + (bid >> 3);
  const int bn = wg % 6;
  const int bm = wg / 6;  // 0..127

  const int wm = (wave >> 1) * 32;  // wave sub-tile origin (M)
  const int wn = (wave & 1) * 64;   // wave sub-tile origin (N)

  const int mrow = lane & 15;
  const int quad = lane >> 4;

  // af[s][i] <- A[(bm*64 + wm + i*16 + mrow)][k0 + s*32 + quad*8 ..+8]
  // bf[s][j] <- B[(bn*128 + wn + j*16 + mrow)][k0 + s*32 + quad*8 ..+8]
  const _Float16* Abase = A + (size_t)(bm * BM + wm + mrow) * HB + quad * 8;
  const _Float16* Bbase = B + (size_t)(bn * BN + wn + mrow) * HB + quad * 8;

  floatx4 acc[2][4] = {};
  half8 a0[2][2], b0[2][4], a1[2][2], b1[2][4];

  LOADF(a0, b0, 0);
#pragma unroll 1
  for (int k0 = 0; k0 < HB; k0 += 128) {
    LOADF(a1, b1, k0 + 64);
    MFMAS(a0, b0);
    const int kn = (k0 + 128 < HB) ? k0 + 128 : 0;  // last iter: dummy reload
    LOADF(a0, b0, kn);
    MFMAS(a1, b1);
  }

  // epilogue: bias + relu, D layout col=lane&15, row=(lane>>4)*4+reg
#pragma unroll
  for (int i = 0; i < 2; ++i) {
#pragma unroll
    for (int j = 0; j < 4; ++j) {
#pragma unroll
      for (int reg = 0; reg < 4; ++reg) {
        const int grow = bm * BM + wm + i * 16 + quad * 4 + reg;
        const int gcol = bn * BN + wn + j * 16 + mrow;
        float v = acc[i][j][reg] + bias[grow];
        v = v > 0.f ? v : 0.f;
        Y[(size_t)grow * NPAD + gcol] = v;
      }
    }
  }
}

// ---------------------------------------------------------------------------
// Kernel 3: epilogue, 4 j-rows per block (2048 blocks). mixed[r][q] (57x57):
//   r=0: 1 at q%7==0 (9 ones)
//   r>=1 (r-1 = c*7+n): q=0 -> (n==6); q>=1 -> y[j,n,7*(7-c)+q-1]
// where y[j,n,p] = Y[j][p*7+n]. d = rsqrt(max(1,rowsum)); out = d_r*mixed*d_q.
// 4 rows -> block out region = 4*3249 floats = 3249 float4 (16B-divisible),
// fully-coalesced vector stores.
// ---------------------------------------------------------------------------
__global__ __launch_bounds__(256) void epilogue_kernel(
    const float* __restrict__ Y, float* __restrict__ out) {
  const int j0 = blockIdx.x * 4;
  __shared__ float ly[4][NR];
  __shared__ float dd[4][NOUT];

#pragma unroll
  for (int jj = 0; jj < 4; ++jj)
    for (int i = threadIdx.x; i < NR; i += 256)
      ly[jj][i] = Y[(size_t)(j0 + jj) * NPAD + i];
  __syncthreads();

  if (threadIdx.x < 4 * NOUT) {
    const int jj = threadIdx.x / NOUT;
    const int r = threadIdx.x % NOUT;
    float s;
    if (r == 0) {
      s = 9.f;
    } else {
      const int c = (r - 1) / 7;
      const int n = (r - 1) % 7;
      const int base = 7 * (7 - c);  // starts[c]
      s = (n == 6) ? 1.f : 0.f;      // mixed[r][0]
      const float* lyj = ly[jj];
#pragma unroll
      for (int q = 0; q < 56; ++q) s += lyj[(base + q) * 7 + n];
    }
    s = s < 1.f ? 1.f : s;  // clip(.,1,None)
    dd[jj][r] = rsqrtf(s);
  }
  __syncthreads();

  // write: 3249 float4 per block, contiguous & 16B-aligned
  float4* ob = (float4*)(out + (size_t)j0 * (NOUT * NOUT));
  for (int v4 = threadIdx.x; v4 < NOUT * NOUT; v4 += 256) {
    float4 o;
#pragma unroll
    for (int e = 0; e < 4; ++e) {
      const int f = v4 * 4 + e;
      const int jj = f / (NOUT * NOUT);
      const int rem = f - jj * (NOUT * NOUT);
      const int r = rem / NOUT;
      const int q = rem - r * NOUT;
      const float* lyj = ly[jj];
      const float* dj = dd[jj];
      float val;
      if (r == 0) {
        val = (q % 7 == 0) ? dj[0] * dj[q] : 0.f;
      } else {
        const int c = (r - 1) / 7;
        const int n = (r - 1) % 7;
        if (q == 0)
          val = (n == 6) ? dj[r] * dj[0] : 0.f;
        else
          val = dj[r] * lyj[(7 * (7 - c) + q - 1) * 7 + n] * dj[q];
      }
      (&o.x)[e] = val;
    }
    ob[v4] = o;
  }
}

// ---------------------------------------------------------------------------
extern "C" void kernel_launch(void* const* d_in, const int* in_sizes, int n_in,
                              void* d_out, int out_size, void* d_ws, size_t ws_size,
                              hipStream_t stream) {
  const float* mat = (const float*)d_in[0];  // (1024,7,7)
  const float* tex = (const float*)d_in[1];  // (1024,15)
  const float* W = (const float*)d_in[2];    // (8192,1024)
  const float* b = (const float*)d_in[3];    // (8192,)
  float* out = (float*)d_out;                // (8192,57,57)

  char* ws = (char*)d_ws;
  _Float16* Xh = (_Float16*)(ws);                                  // 1.5 MB
  _Float16* Wh = (_Float16*)(ws + (size_t)NPAD * HB * 2);          // 16.8 MB
  float* Y = (float*)(ws + (size_t)NPAD * HB * 2 + (size_t)HM * HB * 2);  // 25.2 MB

  prep_kernel<<<NPAD + HM * HB / 4 / 256, 256, 0, stream>>>(
      mat, tex, (const float4*)W, Xh, (half4v*)Wh);
  gemm_kernel<<<HM / BM * (NPAD / BN), 256, 0, stream>>>(Wh, Xh, b, Y);
  epilogue_kernel<<<HM / 4, 256, 0, stream>>>(Y, out);
}

// Round 6
// 196.935 us; speedup vs baseline: 1.1893x; 1.1893x over previous
//
#include <hip/hip_runtime.h>

// Problem constants
#define HB 1024   // NUM_BASIC (GEMM K)
#define HM 8192   // NUM_MIXED (GEMM M)
#define NR 735    // 105*7 actual GEMM N
#define NPAD 768  // padded N
#define NOUT 57   // output is (HM, 57, 57)

// GEMM tiling: 64x128 block tile, BK=32, LDS 24KB dbuf
#define BM 64
#define BN 128
#define BK 32

typedef __attribute__((ext_vector_type(8))) _Float16 half8;
typedef __attribute__((ext_vector_type(4))) float floatx4;

// ---------------------------------------------------------------------------
// Kernel 1: Xh only (W conversion folded into GEMM A-staging).
// x2[r][h] = relu(te[h,t]*mat[h,n,m]) fp16, rows >= NR zeroed,
// K(h)-contiguous. r=(t*7+m)*7+n
// ---------------------------------------------------------------------------
__global__ __launch_bounds__(256) void prep_kernel(
    const float* __restrict__ mat, const float* __restrict__ tex,
    _Float16* __restrict__ Xh) {
  const int r = blockIdx.x;
  const int n = r % 7;
  const int tm = r / 7;
  const int m = tm % 7;
  const int t = tm / 7;
#pragma unroll
  for (int i = 0; i < 4; ++i) {
    const int h = i * 256 + threadIdx.x;
    float v = 0.f;
    if (r < NR) {
      const float mv = mat[h * 49 + n * 7 + m];
      const float te = 1.f / (1.f + expf(-tex[h * 15 + t])) + 1.f;
      v = te * mv;
      v = v > 0.f ? v : 0.f;  // relu
    }
    Xh[r * HB + h] = (_Float16)v;
  }
}

// ---------------------------------------------------------------------------
// Kernel 2: GEMM  Y[j][r] = relu( sum_h (f16)W[j][h]*Xh[r][h] + b[j] )
// M=8192, N=768, K=1024. Grid 768; LDS 24KB -> ~5 blocks/CU (all resident).
// 4 waves, each 32x64 via 2x4 grid of 16x16x32 f16 MFMAs, 2-phase dbuf.
// A-operand: W fp32 reg-staged (T14: global float4 loads issued at top of
// K-step, cvt->ds_write_b128 at the bottom after MFMAs hide the latency)
// into the SAME fp16 [64][32] LDS layout the verified fragment reads use.
// B-operand: global_load_lds width=16 (r1-verified chunk decomposition).
// Race structure identical to r1/r3: stage into p^1 before barrier_i,
// read p^1 after barrier_i; one barrier per K-step.
// Bijective XCD swizzle (768 = 8*96) keeps Xh + W-slice L2/L3-local.
// ---------------------------------------------------------------------------
#define STAGE_B(pp, k0)                                                        \
  do {                                                                         \
    _Pragma("unroll")                                                          \
    for (int it_ = 0; it_ < 2; ++it_) {                                        \
      const int c_ = wave * 2 + it_;                                           \
      const int row_ = c_ * 16 + srow;                                         \
      __builtin_amdgcn_global_load_lds(                                        \
          (const __attribute__((address_space(1))) void*)(                     \
              B + bbase + (size_t)row_ * HB + (k0) + skh),                     \
          (__attribute__((address_space(3))) void*)(&Bs[pp][c_ * 512]),        \
          16, 0, 0);                                                           \
    }                                                                          \
  } while (0)

// cvt 8 fp32 (2x float4) -> half8
#define CVT8(h, r0, r1)                                                        \
  do {                                                                         \
    h[0] = (_Float16)r0.x; h[1] = (_Float16)r0.y;                              \
    h[2] = (_Float16)r0.z; h[3] = (_Float16)r0.w;                              \
    h[4] = (_Float16)r1.x; h[5] = (_Float16)r1.y;                              \
    h[6] = (_Float16)r1.z; h[7] = (_Float16)r1.w;                              \
  } while (0)

__global__ __launch_bounds__(256) void gemm_kernel(
    const float* __restrict__ W,     // [8192][1024] fp32
    const _Float16* __restrict__ B,  // Xh [768][1024] fp16
    const float* __restrict__ bias,  // [8192]
    float* __restrict__ Y) {         // [8192][768]
  __shared__ __align__(16) _Float16 As[2][BM * BK];  // 2 x 4KB
  __shared__ __align__(16) _Float16 Bs[2][BN * BK];  // 2 x 8KB

  const int tid = threadIdx.x;
  const int lane = tid & 63;
  const int wave = tid >> 6;

  // bijective XCD swizzle over 768 blocks (768 = 8 XCD * 96)
  const int bid = blockIdx.x;
  const int wg = (bid & 7) * 96 + (bid >> 3);
  const int bn = wg % 6;
  const int bm = wg / 6;  // 0..127

  const int wm = (wave >> 1) * 32;  // wave sub-tile origin (M)
  const int wn = (wave & 1) * 64;   // wave sub-tile origin (N)

  floatx4 acc[2][4] = {};

  // A reg-staging: wave w owns rows 16w..16w+15 of the 64-row tile.
  // lane l: row = 16w + l/4, k-cols = k0 + (l&3)*8 .. +8 (fp32 -> 2 float4).
  // LDS dst = same fp16 [64][32] layout as the r1-verified Wh staging.
  const int arow = wave * 16 + (lane >> 2);
  const int akh = (lane & 3) * 8;
  const float* Ap = W + (size_t)(bm * BM + arow) * HB + akh;
  const int alds = arow * BK + akh;

  // B staging decomposition (r1-verified): chunk c = 16 rows x 32 halfs (1KB),
  // wave owns chunks {2w, 2w+1}; HW adds lane*16B to the chunk base.
  const int srow = lane >> 2;
  const int skh = (lane & 3) * 8;
  const size_t bbase = (size_t)(bn * BN) * HB;

  const int mrow = lane & 15;
  const int quad = lane >> 4;

  // prologue: stage k=0 into buffer 0 (A via reg+cvt+ds_write, B via gload_lds)
  {
    float4 r0 = *(const float4*)(Ap + 0);
    float4 r1 = *(const float4*)(Ap + 4);
    half8 h;
    CVT8(h, r0, r1);
    *(half8*)(&As[0][alds]) = h;
  }
  STAGE_B(0, 0);
  __syncthreads();  // drains vmcnt + lgkm: tile 0 visible

  int p = 0;
  for (int k0 = 0; k0 < HB; k0 += BK) {
    const int next = k0 + BK;
    float4 r0, r1;
    if (next < HB) {
      r0 = *(const float4*)(Ap + next);  // issued early; MFMAs hide latency
      r1 = *(const float4*)(Ap + next + 4);
      STAGE_B(p ^ 1, next);
    }

    half8 af[2], bf[4];
#pragma unroll
    for (int i = 0; i < 2; ++i)
      af[i] = *(const half8*)(&As[p][(wm + i * 16 + mrow) * BK + quad * 8]);
#pragma unroll
    for (int j = 0; j < 4; ++j)
      bf[j] = *(const half8*)(&Bs[p][(wn + j * 16 + mrow) * BK + quad * 8]);
#pragma unroll
    for (int i = 0; i < 2; ++i)
#pragma unroll
      for (int j = 0; j < 4; ++j)
        acc[i][j] =
            __builtin_amdgcn_mfma_f32_16x16x32_f16(af[i], bf[j], acc[i][j], 0, 0, 0);

    if (next < HB) {
      half8 h;
      CVT8(h, r0, r1);  // compiler waits vmcnt here (loads issued pre-MFMA)
      *(half8*)(&As[p ^ 1][alds]) = h;
    }
    __syncthreads();  // drains B-prefetch vmcnt + A ds_write; all done with p
    p ^= 1;
  }

  // epilogue: bias + relu, D layout col=lane&15, row=(lane>>4)*4+reg
#pragma unroll
  for (int i = 0; i < 2; ++i) {
#pragma unroll
    for (int j = 0; j < 4; ++j) {
#pragma unroll
      for (int reg = 0; reg < 4; ++reg) {
        const int grow = bm * BM + wm + i * 16 + quad * 4 + reg;
        const int gcol = bn * BN + wn + j * 16 + mrow;
        float v = acc[i][j][reg] + bias[grow];
        v = v > 0.f ? v : 0.f;
        Y[(size_t)grow * NPAD + gcol] = v;
      }
    }
  }
}

// ---------------------------------------------------------------------------
// Kernel 3: epilogue, 4 j-rows per block (2048 blocks). mixed[r][q] (57x57):
//   r=0: 1 at q%7==0 (9 ones)
//   r>=1 (r-1 = c*7+n): q=0 -> (n==6); q>=1 -> y[j,n,7*(7-c)+q-1]
// where y[j,n,p] = Y[j][p*7+n]. d = rsqrt(max(1,rowsum)); out = d_r*mixed*d_q.
// 4 rows -> block out region = 4*3249 floats = 3249 float4 (16B-divisible),
// fully-coalesced vector stores.
// ---------------------------------------------------------------------------
__global__ __launch_bounds__(256) void epilogue_kernel(
    const float* __restrict__ Y, float* __restrict__ out) {
  const int j0 = blockIdx.x * 4;
  __shared__ float ly[4][NR];
  __shared__ float dd[4][NOUT];

#pragma unroll
  for (int jj = 0; jj < 4; ++jj)
    for (int i = threadIdx.x; i < NR; i += 256)
      ly[jj][i] = Y[(size_t)(j0 + jj) * NPAD + i];
  __syncthreads();

  if (threadIdx.x < 4 * NOUT) {
    const int jj = threadIdx.x / NOUT;
    const int r = threadIdx.x % NOUT;
    float s;
    if (r == 0) {
      s = 9.f;
    } else {
      const int c = (r - 1) / 7;
      const int n = (r - 1) % 7;
      const int base = 7 * (7 - c);  // starts[c]
      s = (n == 6) ? 1.f : 0.f;      // mixed[r][0]
      const float* lyj = ly[jj];
#pragma unroll
      for (int q = 0; q < 56; ++q) s += lyj[(base + q) * 7 + n];
    }
    s = s < 1.f ? 1.f : s;  // clip(.,1,None)
    dd[jj][r] = rsqrtf(s);
  }
  __syncthreads();

  // write: 3249 float4 per block, contiguous & 16B-aligned
  float4* ob = (float4*)(out + (size_t)j0 * (NOUT * NOUT));
  for (int v4 = threadIdx.x; v4 < NOUT * NOUT; v4 += 256) {
    float4 o;
#pragma unroll
    for (int e = 0; e < 4; ++e) {
      const int f = v4 * 4 + e;
      const int jj = f / (NOUT * NOUT);
      const int rem = f - jj * (NOUT * NOUT);
      const int r = rem / NOUT;
      const int q = rem - r * NOUT;
      const float* lyj = ly[jj];
      const float* dj = dd[jj];
      float val;
      if (r == 0) {
        val = (q % 7 == 0) ? dj[0] * dj[q] : 0.f;
      } else {
        const int c = (r - 1) / 7;
        const int n = (r - 1) % 7;
        if (q == 0)
          val = (n == 6) ? dj[r] * dj[0] : 0.f;
        else
          val = dj[r] * lyj[(7 * (7 - c) + q - 1) * 7 + n] * dj[q];
      }
      (&o.x)[e] = val;
    }
    ob[v4] = o;
  }
}

// ---------------------------------------------------------------------------
extern "C" void kernel_launch(void* const* d_in, const int* in_sizes, int n_in,
                              void* d_out, int out_size, void* d_ws, size_t ws_size,
                              hipStream_t stream) {
  const float* mat = (const float*)d_in[0];  // (1024,7,7)
  const float* tex = (const float*)d_in[1];  // (1024,15)
  const float* W = (const float*)d_in[2];    // (8192,1024)
  const float* b = (const float*)d_in[3];    // (8192,)
  float* out = (float*)d_out;                // (8192,57,57)

  char* ws = (char*)d_ws;
  _Float16* Xh = (_Float16*)(ws);                          // 1.5 MB
  float* Y = (float*)(ws + (size_t)NPAD * HB * 2);         // 25.2 MB

  prep_kernel<<<NPAD, 256, 0, stream>>>(mat, tex, Xh);
  gemm_kernel<<<HM / BM * (NPAD / BN), 256, 0, stream>>>(W, Xh, b, Y);
  epilogue_kernel<<<HM / 4, 256, 0, stream>>>(Y, out);
}

// Round 7
// 188.772 us; speedup vs baseline: 1.2408x; 1.0432x over previous
//
#include <hip/hip_runtime.h>

// Problem constants
#define HB 1024   // NUM_BASIC (GEMM K)
#define HM 8192   // NUM_MIXED (GEMM M)
#define NR 735    // 105*7 actual GEMM N
#define NPAD 768  // padded N
#define NOUT 57   // output is (HM, 57, 57)

// GEMM tiling: 64x128 block tile, BK=32, 3-deep LDS pipeline (36KB)
#define BM 64
#define BN 128
#define BK 32

typedef __attribute__((ext_vector_type(8))) _Float16 half8;
typedef __attribute__((ext_vector_type(4))) _Float16 half4v;
typedef __attribute__((ext_vector_type(4))) float floatx4;

// ---------------------------------------------------------------------------
// Kernel 1 (merged preps, r1-verified):
//  blocks [0, NPAD):        x2[r][h] = relu(te[h,t]*mat[h,n,m]) fp16,
//                           rows >= NR zeroed, K(h)-contiguous. r=(t*7+m)*7+n
//  blocks [NPAD, NPAD+8192): W fp32 -> fp16
// ---------------------------------------------------------------------------
__global__ __launch_bounds__(256) void prep_kernel(
    const float* __restrict__ mat, const float* __restrict__ tex,
    const float4* __restrict__ W,
    _Float16* __restrict__ Xh, half4v* __restrict__ Wh) {
  const int blk = blockIdx.x;
  if (blk < NPAD) {
    const int r = blk;
    const int n = r % 7;
    const int tm = r / 7;
    const int m = tm % 7;
    const int t = tm / 7;
#pragma unroll
    for (int i = 0; i < 4; ++i) {
      const int h = i * 256 + threadIdx.x;
      float v = 0.f;
      if (r < NR) {
        const float mv = mat[h * 49 + n * 7 + m];
        const float te = 1.f / (1.f + expf(-tex[h * 15 + t])) + 1.f;
        v = te * mv;
        v = v > 0.f ? v : 0.f;  // relu
      }
      Xh[r * HB + h] = (_Float16)v;
    }
  } else {
    const int idx = (blk - NPAD) * 256 + threadIdx.x;
    const float4 v = W[idx];
    half4v h;
    h.x = (_Float16)v.x;
    h.y = (_Float16)v.y;
    h.z = (_Float16)v.z;
    h.w = (_Float16)v.w;
    Wh[idx] = h;
  }
}

// ---------------------------------------------------------------------------
// Kernel 2: GEMM  Y[j][r] = relu( sum_h Wh[j][h]*Xh[r][h] + b[j] )
// M=8192, N=768, K=1024. Grid 768 = 3 blocks/CU. LDS 36KB (3 x 12KB).
// 4 waves, each 32x64 via 2x4 grid of 16x16x32 f16 MFMAs.
// T4 counted-vmcnt pipeline (m218: counted-vs-drain0 is THE 2-phase gain):
//   stage s -> buffer s%3; iter i waits vmcnt(3) (stage i complete, stage
//   i+1's 3 loads/wave stay IN FLIGHT across the raw s_barrier), then
//   issues stage i+2 and computes buffer i%3. Tail peeled with vmcnt(0).
// Safety: buffer (i+2)%3 was ds_read at iter i-1; each wave's lgkm waits
// before its MFMAs complete those reads before it reaches iter i's barrier,
// so post-barrier restaging cannot race. Exactly 3 VMEM ops/wave/stage
// (1 A + 2 B global_load_lds), no other in-loop VMEM -> count is exact.
// Every asm waitcnt is fenced with sched_barrier(0) (rule #18).
// Bijective XCD swizzle (768 = 8*96): A-slice 2MB + B 1.5MB L2-resident.
// ---------------------------------------------------------------------------
#define STAGE(pp, k0)                                                          \
  do {                                                                         \
    const int arow_ = wave * 16 + srow;                                        \
    __builtin_amdgcn_global_load_lds(                                          \
        (const __attribute__((address_space(1))) void*)(                       \
            A + abase + (size_t)arow_ * HB + (k0) + skh),                      \
        (__attribute__((address_space(3))) void*)(&As[pp][wave * 512]),        \
        16, 0, 0);                                                             \
    _Pragma("unroll")                                                          \
    for (int it_ = 0; it_ < 2; ++it_) {                                        \
      const int c_ = wave * 2 + it_;                                           \
      const int brow_ = c_ * 16 + srow;                                        \
      __builtin_amdgcn_global_load_lds(                                        \
          (const __attribute__((address_space(1))) void*)(                     \
              B + bbase + (size_t)brow_ * HB + (k0) + skh),                    \
          (__attribute__((address_space(3))) void*)(&Bs[pp][c_ * 512]),        \
          16, 0, 0);                                                           \
    }                                                                          \
  } while (0)

#define COMPUTE(pp)                                                            \
  do {                                                                         \
    half8 af[2], bf[4];                                                        \
    _Pragma("unroll")                                                          \
    for (int i_ = 0; i_ < 2; ++i_)                                             \
      af[i_] = *(const half8*)(&As[pp][(wm + i_ * 16 + mrow) * BK + quad * 8]);\
    _Pragma("unroll")                                                          \
    for (int j_ = 0; j_ < 4; ++j_)                                             \
      bf[j_] = *(const half8*)(&Bs[pp][(wn + j_ * 16 + mrow) * BK + quad * 8]);\
    _Pragma("unroll")                                                          \
    for (int i_ = 0; i_ < 2; ++i_)                                             \
      _Pragma("unroll")                                                        \
      for (int j_ = 0; j_ < 4; ++j_)                                           \
        acc[i_][j_] = __builtin_amdgcn_mfma_f32_16x16x32_f16(                  \
            af[i_], bf[j_], acc[i_][j_], 0, 0, 0);                             \
  } while (0)

__global__ __launch_bounds__(256) void gemm_kernel(
    const _Float16* __restrict__ A,  // Wh [8192][1024]
    const _Float16* __restrict__ B,  // Xh [768][1024]
    const float* __restrict__ bias,  // [8192]
    float* __restrict__ Y) {         // [8192][768]
  __shared__ __align__(16) _Float16 As[3][BM * BK];  // 3 x 4KB
  __shared__ __align__(16) _Float16 Bs[3][BN * BK];  // 3 x 8KB

  const int tid = threadIdx.x;
  const int lane = tid & 63;
  const int wave = tid >> 6;

  // bijective XCD swizzle over 768 blocks (768 = 8 XCD * 96)
  const int bid = blockIdx.x;
  const int wg = (bid & 7) * 96 + (bid >> 3);
  const int bn = wg % 6;
  const int bm = wg / 6;  // 0..127

  const int wm = (wave >> 1) * 32;  // wave sub-tile origin (M)
  const int wn = (wave & 1) * 64;   // wave sub-tile origin (N)

  floatx4 acc[2][4] = {};

  // staging decomposition (r1-verified): chunk = 16 rows x 32 halfs (1KB);
  // lane l covers chunk bytes l*16 -> row = l/4, k-half off = (l&3)*8.
  const int srow = lane >> 2;
  const int skh = (lane & 3) * 8;
  const size_t abase = (size_t)(bm * BM) * HB;
  const size_t bbase = (size_t)(bn * BN) * HB;

  const int mrow = lane & 15;
  const int quad = lane >> 4;

  // prologue: two stages in flight
  STAGE(0, 0);
  STAGE(1, BK);

  int p = 0;
#pragma unroll 1
  for (int k0 = 0; k0 < HB - BK; k0 += BK) {
    // stage (k0/BK) complete; stage (k0/BK + 1) stays in flight
    asm volatile("s_waitcnt vmcnt(3)" ::: "memory");
    __builtin_amdgcn_sched_barrier(0);
    __builtin_amdgcn_s_barrier();
    __builtin_amdgcn_sched_barrier(0);

    const int pn = (p + 2 >= 3) ? p - 1 : p + 2;
    if (k0 + 2 * BK < HB) STAGE(pn, k0 + 2 * BK);

    COMPUTE(p);
    p = (p == 2) ? 0 : p + 1;
  }

  // tail: last stage must fully drain
  asm volatile("s_waitcnt vmcnt(0)" ::: "memory");
  __builtin_amdgcn_sched_barrier(0);
  __builtin_amdgcn_s_barrier();
  __builtin_amdgcn_sched_barrier(0);
  COMPUTE(p);

  // epilogue: bias + relu, D layout col=lane&15, row=(lane>>4)*4+reg
#pragma unroll
  for (int i = 0; i < 2; ++i) {
#pragma unroll
    for (int j = 0; j < 4; ++j) {
#pragma unroll
      for (int reg = 0; reg < 4; ++reg) {
        const int grow = bm * BM + wm + i * 16 + quad * 4 + reg;
        const int gcol = bn * BN + wn + j * 16 + mrow;
        float v = acc[i][j][reg] + bias[grow];
        v = v > 0.f ? v : 0.f;
        Y[(size_t)grow * NPAD + gcol] = v;
      }
    }
  }
}

// ---------------------------------------------------------------------------
// Kernel 3: epilogue, 4 j-rows per block (2048 blocks). mixed[r][q] (57x57):
//   r=0: 1 at q%7==0 (9 ones)
//   r>=1 (r-1 = c*7+n): q=0 -> (n==6); q>=1 -> y[j,n,7*(7-c)+q-1]
// where y[j,n,p] = Y[j][p*7+n]. d = rsqrt(max(1,rowsum)); out = d_r*mixed*d_q.
// 4 rows -> block out region = 4*3249 floats = 3249 float4 (16B-divisible),
// fully-coalesced vector stores.
// ---------------------------------------------------------------------------
__global__ __launch_bounds__(256) void epilogue_kernel(
    const float* __restrict__ Y, float* __restrict__ out) {
  const int j0 = blockIdx.x * 4;
  __shared__ float ly[4][NR];
  __shared__ float dd[4][NOUT];

#pragma unroll
  for (int jj = 0; jj < 4; ++jj)
    for (int i = threadIdx.x; i < NR; i += 256)
      ly[jj][i] = Y[(size_t)(j0 + jj) * NPAD + i];
  __syncthreads();

  if (threadIdx.x < 4 * NOUT) {
    const int jj = threadIdx.x / NOUT;
    const int r = threadIdx.x % NOUT;
    float s;
    if (r == 0) {
      s = 9.f;
    } else {
      const int c = (r - 1) / 7;
      const int n = (r - 1) % 7;
      const int base = 7 * (7 - c);  // starts[c]
      s = (n == 6) ? 1.f : 0.f;      // mixed[r][0]
      const float* lyj = ly[jj];
#pragma unroll
      for (int q = 0; q < 56; ++q) s += lyj[(base + q) * 7 + n];
    }
    s = s < 1.f ? 1.f : s;  // clip(.,1,None)
    dd[jj][r] = rsqrtf(s);
  }
  __syncthreads();

  // write: 3249 float4 per block, contiguous & 16B-aligned
  float4* ob = (float4*)(out + (size_t)j0 * (NOUT * NOUT));
  for (int v4 = threadIdx.x; v4 < NOUT * NOUT; v4 += 256) {
    float4 o;
#pragma unroll
    for (int e = 0; e < 4; ++e) {
      const int f = v4 * 4 + e;
      const int jj = f / (NOUT * NOUT);
      const int rem = f - jj * (NOUT * NOUT);
      const int r = rem / NOUT;
      const int q = rem - r * NOUT;
      const float* lyj = ly[jj];
      const float* dj = dd[jj];
      float val;
      if (r == 0) {
        val = (q % 7 == 0) ? dj[0] * dj[q] : 0.f;
      } else {
        const int c = (r - 1) / 7;
        const int n = (r - 1) % 7;
        if (q == 0)
          val = (n == 6) ? dj[r] * dj[0] : 0.f;
        else
          val = dj[r] * lyj[(7 * (7 - c) + q - 1) * 7 + n] * dj[q];
      }
      (&o.x)[e] = val;
    }
    ob[v4] = o;
  }
}

// ---------------------------------------------------------------------------
extern "C" void kernel_launch(void* const* d_in, const int* in_sizes, int n_in,
                              void* d_out, int out_size, void* d_ws, size_t ws_size,
                              hipStream_t stream) {
  const float* mat = (const float*)d_in[0];  // (1024,7,7)
  const float* tex = (const float*)d_in[1];  // (1024,15)
  const float* W = (const float*)d_in[2];    // (8192,1024)
  const float* b = (const float*)d_in[3];    // (8192,)
  float* out = (float*)d_out;                // (8192,57,57)

  char* ws = (char*)d_ws;
  _Float16* Xh = (_Float16*)(ws);                                  // 1.5 MB
  _Float16* Wh = (_Float16*)(ws + (size_t)NPAD * HB * 2);          // 16.8 MB
  float* Y = (float*)(ws + (size_t)NPAD * HB * 2 + (size_t)HM * HB * 2);  // 25.2 MB

  prep_kernel<<<NPAD + HM * HB / 4 / 256, 256, 0, stream>>>(
      mat, tex, (const float4*)W, Xh, (half4v*)Wh);
  gemm_kernel<<<HM / BM * (NPAD / BN), 256, 0, stream>>>(Wh, Xh, b, Y);
  epilogue_kernel<<<HM / 4, 256, 0, stream>>>(Y, out);
}